// Round 9
// baseline (101.031 us; speedup 1.0000x reference)
//
#include <hip/hip_runtime.h>

#define NB   32
#define NCI  128
#define NH   64
#define NW   64
#define NCO  256
#define NOH  62
#define NOW  62

typedef __attribute__((ext_vector_type(8))) short bf16x8;           // 8 bf16 (4 VGPRs)
typedef __attribute__((ext_vector_type(8))) unsigned short u16x8;
typedef __attribute__((ext_vector_type(4))) float f32x4;

typedef __attribute__((address_space(1))) const unsigned int glb_u32_t;
typedef __attribute__((address_space(3))) unsigned int lds_u32_t;

// fp32 -> bf16 bits, round-to-nearest-even (finite inputs)
__device__ __forceinline__ unsigned short f2bf(float f) {
  unsigned int u = __float_as_uint(f);
  u = u + 0x7FFFu + ((u >> 16) & 1u);
  return (unsigned short)(u >> 16);
}

__device__ __forceinline__ void gload_lds16(const unsigned short* g, unsigned short* l) {
  __builtin_amdgcn_global_load_lds((glb_u32_t*)g, (lds_u32_t*)l, 16, 0, 0);
}

// x[b][ci][h][w] fp32 -> xt[b][h][w][ci] bf16, transposed through LDS.
__global__ __launch_bounds__(256) void cvt_x_kernel(const float* __restrict__ x,
                                                    unsigned short* __restrict__ xt) {
  __shared__ unsigned short l[64 * 130];   // 16640 B
  const int tid = threadIdx.x;
  const int b = blockIdx.x >> 6, h = blockIdx.x & 63;
  const int w0 = tid & 63, c0 = tid >> 6;
  const float* src = x + ((size_t)b * NCI * NH + h) * NW;
  #pragma unroll
  for (int g = 0; g < 32; ++g) {
    int ci = g * 4 + c0;
    l[w0 * 130 + ci] = f2bf(src[(size_t)ci * (NH * NW) + w0]);
  }
  __syncthreads();
  unsigned short* dst = xt + ((size_t)b * NH + h) * NW * NCI;
  #pragma unroll
  for (int it = 0; it < 4; ++it) {
    int gidx = it * 2048 + tid * 8;
    int w = gidx >> 7, ci0 = gidx & 127;
    const unsigned int* lw = (const unsigned int*)(l + w * 130 + ci0);
    union { u16x8 v; unsigned int u[4]; } t;
    t.u[0] = lw[0]; t.u[1] = lw[1]; t.u[2] = lw[2]; t.u[3] = lw[3];
    *(u16x8*)(dst + w * NCI + ci0) = t.v;
  }
}

// W[co][ci][kh][kw] fp32 -> wt[k][co][ci] bf16, coalesced 16B stores
__global__ __launch_bounds__(256) void cvt_w_kernel(const float* __restrict__ wsrc,
                                                    unsigned short* __restrict__ wt) {
  int t = blockIdx.x * 256 + threadIdx.x;            // 0 .. 9*256*16-1
  int oc = t & 15, co = (t >> 4) & 255, k = t >> 12;
  const float* src = wsrc + ((size_t)co * NCI + oc * 8) * 9 + k;
  u16x8 v;
  #pragma unroll
  for (int j = 0; j < 8; ++j) v[j] = f2bf(src[j * 9]);
  *(u16x8*)(wt + ((size_t)k * NCO + co) * NCI + oc * 8) = v;
}

// Implicit direct conv, bf16 MFMA 16x16x32 — PAIR-WINDOW schedule.
// Block: 256 thr (4 waves, wn 0..3), tile 128 cout (coutg half) x 4 oh x 64 ow.
// Wave tile 128co x 64pix (8m x 4n, intensity 42.7 FLOP/LDS-byte, verified).
// 36 taps t = cic*9 + tap9; ONE barrier per PAIR of taps (18 barriers):
//   [vmcnt(0); s_barrier; sched_barrier] readsA; MFMA_A; stage(t+2),(t+3);
//   readsB; MFMA_B  -- no barrier between taps: compiler sinks readsB under
//   MFMA_A, spreading the LDS-read burst that serialized round 8's windows.
// LDS 80 KB -> 2 blocks/CU:
//   xs: 2 x [6r][64w][4oct][8] (24 KB, parity cic&1)   bytes [0, 49152)
//   ws: 4 x [128co][4oct][8]   (8 KB,  buf t&3)        bytes [49152, 81920)
// WAR: pair reads bufs t&3,(t+1)&3; stages write (t+2)&3,(t+3)&3 (disjoint);
// previous occupants last read one pair ago, fenced by this pair's barrier.
// vmcnt(0) at pair top drains loads issued a full window earlier (~free).
// Octet swizzle baked into gload_lds SOURCE (LDS dest linear); same XOR on
// read; measured 0 conflicts. xs w-overreads (w up to 65) stay in-allocation
// and feed masked ow>=62 outputs only.
__global__ __launch_bounds__(256, 2) void conv_mfma_kernel(
    const unsigned short* __restrict__ xt, const unsigned short* __restrict__ wt,
    const float* __restrict__ bias, float* __restrict__ out) {
  __shared__ unsigned short smem[40960];   // 81920 B

  const int tid  = threadIdx.x;
  const int lane = tid & 63;
  const int wid  = tid >> 6;    // 0..3
  const int wn   = wid;         // output row within quad (0..3)
  const int l15  = lane & 15;
  const int lo   = lane >> 4;   // k-octet group

  // XCD-bijective swizzle: grid 1024 = 8 * 128 exactly.
  const int bid0  = blockIdx.x;
  const int bid   = (bid0 & 7) * 128 + (bid0 >> 3);
  const int coutg = bid & 1;               // ((b*16 + ohg)*2 + coutg)
  const int ohg   = (bid >> 1) & 15;
  const int b     = bid >> 5;
  const int cbase = coutg * 128;
  const int oh0   = ohg * 4;               // 0..60 (ohg 15: rows 62,63 masked)

  f32x4 acc[8][4];
  #pragma unroll
  for (int mi = 0; mi < 8; ++mi)
    #pragma unroll
    for (int ni = 0; ni < 4; ++ni)
      acc[mi][ni] = (f32x4){0.f, 0.f, 0.f, 0.f};

  // per-lane LDS read base components (bytes)
  const char* sm = (const char*)smem;
  const int af_lane = l15 * 64 + ((lo ^ ((l15 >> 1) & 3)) << 4);

  // persistent staging source pointers
  const size_t xbase = (size_t)b * NH * NW * NCI;
  const unsigned short* xsrc[6];
  #pragma unroll
  for (int i = 0; i < 6; ++i) {
    int e = (wid * 6 + i) * 64 + lane;     // 0..1535
    int o = e & 3, w = (e >> 2) & 63, r = e >> 8;    // r 0..5
    int row = oh0 + r; if (row > 63) row = 63;       // clamp (masked outputs)
    xsrc[i] = xt + xbase + ((size_t)row * NW + w) * NCI
            + ((o ^ ((w >> 1) & 3)) * 8);
  }
  const unsigned short* wsrc2[2];
  #pragma unroll
  for (int i = 0; i < 2; ++i) {
    int e = (wid * 2 + i) * 64 + lane;     // 0..511
    int o = e & 3, co = e >> 2;            // co 0..127
    wsrc2[i] = wt + (size_t)(cbase + co) * NCI + ((o ^ ((co >> 1) & 3)) * 8);
  }

  // stage ws for global tap t (bufq static at call sites): 2 gload/thread
  auto stage_w = [&](int bufq, int t9, int c) {
    unsigned short* dst = smem + 24576 + bufq * 4096;
    const size_t so = (size_t)t9 * NCO * NCI + c * 32;
    #pragma unroll
    for (int i = 0; i < 2; ++i)
      gload_lds16(wsrc2[i] + so, dst + ((wid * 2 + i) * 64 + lane) * 8);
  };
  // stage xs chunk c into parity c&1: 6 gload/thread
  auto stage_x = [&](int c) {
    unsigned short* dst = smem + (c & 1) * 12288;
    #pragma unroll
    for (int i = 0; i < 6; ++i)
      gload_lds16(xsrc[i] + c * 32, dst + ((wid * 6 + i) * 64 + lane) * 8);
  };

  // one tap's reads + MFMAs (bufq compile-time at each call site)
  auto tap_compute = [&](int bufq, int t9, int c) {
    const int kh = t9 / 3, kw = t9 % 3;
    const int r  = wn + kh;                          // 0..5
    const int w9 = l15 + kw;
    const int bfl = w9 * 64 + ((lo ^ ((w9 >> 1) & 3)) << 4);
    const char* wsp = sm + 49152 + bufq * 8192;
    const char* xsp = sm + (c & 1) * 24576 + r * 4096;
    bf16x8 af[8], bfv[4];
    #pragma unroll
    for (int mi = 0; mi < 8; ++mi)
      af[mi] = *(const bf16x8*)(wsp + mi * 1024 + af_lane);
    #pragma unroll
    for (int ni = 0; ni < 4; ++ni)
      bfv[ni] = *(const bf16x8*)(xsp + ni * 1024 + bfl);
    __builtin_amdgcn_s_setprio(1);                   // T5
    #pragma unroll
    for (int mi = 0; mi < 8; ++mi)
      #pragma unroll
      for (int ni = 0; ni < 4; ++ni)
        acc[mi][ni] = __builtin_amdgcn_mfma_f32_16x16x32_bf16(
            af[mi], bfv[ni], acc[mi][ni], 0, 0, 0);
    __builtin_amdgcn_s_setprio(0);
  };

  // prologue: taps 0,1 + xs chunk 0
  stage_w(0, 0, 0);
  stage_w(1, 1, 0);
  stage_x(0);

  for (int h = 0; h < 9; ++h) {            // runtime loop (anti-spill)
    #pragma unroll
    for (int jp = 0; jp < 2; ++jp) {       // bufq pattern static per jp
      const int ta  = h * 4 + jp * 2;      // even tap of the pair
      const int tb  = ta + 1;
      const int t9a = ta % 9, ca = ta / 9;
      const int t9b = tb % 9, cb = tb / 9;
      const int qa  = jp * 2, qb = jp * 2 + 1;          // ta&3, tb&3 (static)
      const int qa2 = (jp * 2 + 2) & 3, qb2 = (jp * 2 + 3) & 3;

      asm volatile("s_waitcnt vmcnt(0)" ::: "memory");  // drains prev-pair
      __builtin_amdgcn_s_barrier();                     // stages (~free)
      __builtin_amdgcn_sched_barrier(0);

      tap_compute(qa, t9a, ca);            // reads A + 32 MFMA

      // stage next pair (bufs qa2/qb2 disjoint from qa/qb; WAR fenced above)
      if (ta + 2 <= 35) stage_w(qa2, (ta + 2) % 9, (ta + 2) / 9);
      if (tb + 2 <= 35) stage_w(qb2, (tb + 2) % 9, (tb + 2) / 9);
      if (t9a == 4 && ca < 3) stage_x(ca + 1);   // taps 4, 22
      if (t9b == 4 && cb < 3) stage_x(cb + 1);   // taps 13, 31

      tap_compute(qb, t9b, cb);            // reads B (sink under MFMA_A) + 32 MFMA
    }
  }

  // epilogue: D row = lo*4 + reg (cout), col = l15 (ow)
  const int oh = oh0 + wn;
  if (oh < NOH) {
    #pragma unroll
    for (int mi = 0; mi < 8; ++mi) {
      int co0 = cbase + mi * 16 + lo * 4;
      const f32x4 bv = *(const f32x4*)(bias + co0);
      #pragma unroll
      for (int ni = 0; ni < 4; ++ni) {
        int ow = ni * 16 + l15;
        if (ow < NOW) {
          size_t o0 = (((size_t)b * NCO + co0) * NOH + oh) * NOW + ow;
          const size_t cs = (size_t)NOH * NOW;
          out[o0]          = acc[mi][ni][0] + bv[0];
          out[o0 + cs]     = acc[mi][ni][1] + bv[1];
          out[o0 + 2 * cs] = acc[mi][ni][2] + bv[2];
          out[o0 + 3 * cs] = acc[mi][ni][3] + bv[3];
        }
      }
    }
  }
}

// Safety-net: correct fp32 direct conv (used only if ws_size too small)
__global__ __launch_bounds__(256) void conv_naive_kernel(
    const float* __restrict__ x, const float* __restrict__ w,
    const float* __restrict__ bias, float* __restrict__ out) {
  long t = (long)blockIdx.x * 256 + threadIdx.x;
  const long total = (long)NB * NCO * NOH * NOW;
  if (t >= total) return;
  int ow = (int)(t % NOW);
  int oh = (int)((t / NOW) % NOH);
  int co = (int)((t / ((long)NOW * NOH)) % NCO);
  int b  = (int)(t / ((long)NOW * NOH * NCO));
  float acc = bias[co];
  for (int ci = 0; ci < NCI; ++ci) {
    const float* xp = x + (((size_t)b * NCI + ci) * NH + oh) * NW + ow;
    const float* wp = w + ((size_t)co * NCI + ci) * 9;
    #pragma unroll
    for (int kh = 0; kh < 3; ++kh)
      #pragma unroll
      for (int kw = 0; kw < 3; ++kw)
        acc += xp[kh * NW + kw] * wp[kh * 3 + kw];
  }
  out[t] = acc;
}

extern "C" void kernel_launch(void* const* d_in, const int* in_sizes, int n_in,
                              void* d_out, int out_size, void* d_ws, size_t ws_size,
                              hipStream_t stream) {
  const float* x    = (const float*)d_in[0];
  const float* w    = (const float*)d_in[1];
  const float* bias = (const float*)d_in[2];
  float* out        = (float*)d_out;

  const size_t WT_BYTES = (size_t)9 * NCO * NCI * 2;             // 589824
  const size_t XT_BYTES = (size_t)NB * NH * NW * NCI * 2;        // 33554432

  if (ws_size >= WT_BYTES + XT_BYTES) {
    unsigned short* wt = (unsigned short*)d_ws;
    unsigned short* xt = (unsigned short*)((char*)d_ws + WT_BYTES);
    cvt_w_kernel<<<(9 * NCO * 16) / 256, 256, 0, stream>>>(w, wt);
    cvt_x_kernel<<<NB * NH, 256, 0, stream>>>(x, xt);
    conv_mfma_kernel<<<2 * 16 * NB, 256, 0, stream>>>(xt, wt, bias, out);
  } else {
    const long total = (long)NB * NCO * NOH * NOW;
    conv_naive_kernel<<<(int)((total + 255) / 256), 256, 0, stream>>>(x, w, bias, out);
  }
}

// Round 10
// 97.846 us; speedup vs baseline: 1.0325x; 1.0325x over previous
//
#include <hip/hip_runtime.h>

#define NB   32
#define NCI  128
#define NH   64
#define NW   64
#define NCO  256
#define NOH  62
#define NOW  62

typedef __attribute__((ext_vector_type(8))) short bf16x8;           // 8 bf16 (4 VGPRs)
typedef __attribute__((ext_vector_type(8))) unsigned short u16x8;
typedef __attribute__((ext_vector_type(4))) float f32x4;

typedef __attribute__((address_space(1))) const unsigned int glb_u32_t;
typedef __attribute__((address_space(3))) unsigned int lds_u32_t;

// fp32 -> bf16 bits, round-to-nearest-even (finite inputs)
__device__ __forceinline__ unsigned short f2bf(float f) {
  unsigned int u = __float_as_uint(f);
  u = u + 0x7FFFu + ((u >> 16) & 1u);
  return (unsigned short)(u >> 16);
}

__device__ __forceinline__ void gload_lds16(const unsigned short* g, unsigned short* l) {
  __builtin_amdgcn_global_load_lds((glb_u32_t*)g, (lds_u32_t*)l, 16, 0, 0);
}

// x[b][ci][h][w] fp32 -> xt[b][h][w][ci] bf16, transposed through LDS.
__global__ __launch_bounds__(256) void cvt_x_kernel(const float* __restrict__ x,
                                                    unsigned short* __restrict__ xt) {
  __shared__ unsigned short l[64 * 130];   // 16640 B
  const int tid = threadIdx.x;
  const int b = blockIdx.x >> 6, h = blockIdx.x & 63;
  const int w0 = tid & 63, c0 = tid >> 6;
  const float* src = x + ((size_t)b * NCI * NH + h) * NW;
  #pragma unroll
  for (int g = 0; g < 32; ++g) {
    int ci = g * 4 + c0;
    l[w0 * 130 + ci] = f2bf(src[(size_t)ci * (NH * NW) + w0]);
  }
  __syncthreads();
  unsigned short* dst = xt + ((size_t)b * NH + h) * NW * NCI;
  #pragma unroll
  for (int it = 0; it < 4; ++it) {
    int gidx = it * 2048 + tid * 8;
    int w = gidx >> 7, ci0 = gidx & 127;
    const unsigned int* lw = (const unsigned int*)(l + w * 130 + ci0);
    union { u16x8 v; unsigned int u[4]; } t;
    t.u[0] = lw[0]; t.u[1] = lw[1]; t.u[2] = lw[2]; t.u[3] = lw[3];
    *(u16x8*)(dst + w * NCI + ci0) = t.v;
  }
}

// W[co][ci][kh][kw] fp32 -> wt[k][co][ci] bf16, coalesced 16B stores
__global__ __launch_bounds__(256) void cvt_w_kernel(const float* __restrict__ wsrc,
                                                    unsigned short* __restrict__ wt) {
  int t = blockIdx.x * 256 + threadIdx.x;            // 0 .. 9*256*16-1
  int oc = t & 15, co = (t >> 4) & 255, k = t >> 12;
  const float* src = wsrc + ((size_t)co * NCI + oc * 8) * 9 + k;
  u16x8 v;
  #pragma unroll
  for (int j = 0; j < 8; ++j) v[j] = f2bf(src[j * 9]);
  *(u16x8*)(wt + ((size_t)k * NCO + co) * NCI + oc * 8) = v;
}

// Implicit direct conv, bf16 MFMA 16x16x32 — m201-style per-tap phases:
//   reads(t) BEFORE barrier (overlap other waves' MFMA(t-1) via barrier
//   skew), counted vmcnt, s_barrier, lgkmcnt(0)+sched_barrier, 32 MFMA.
// Block: 256 thr (4 waves wn 0..3), tile 128 cout x 4 oh x 64 ow.
// Wave tile 128co x 64pix (8m x 4n). 36 taps t = c*9 + t9.
// LDS 80 KB -> 2 blocks/CU:
//   xs: 2 x [6r][64w][4oct][8] (24 KB, parity c&1)  bytes [0, 49152)
//   ws: 4 x [128co][4oct][8]   (8 KB,  buf t&3)     bytes [49152, 81920)
// Staging depth 2 (stage(t+2) at tap t). WAR: stage(t+2) writes (t-2)&3,
// whose reads finished before barrier(t-2); xs stage at t9==3 writes the
// opposite parity, first read 6 taps later. vmcnt: 2 normal / 8 while
// stage_x in flight (t9==3,4; retired at t9==5's vmcnt(2)) / 0 at t>=34.
// Octet swizzle baked into gload_lds SOURCE (LDS dest linear); same XOR on
// read; measured 0 conflicts. xs w-overreads (w up to 65) stay inside the
// 80 KB allocation and feed masked ow>=62 outputs only.
__global__ __launch_bounds__(256, 2) void conv_mfma_kernel(
    const unsigned short* __restrict__ xt, const unsigned short* __restrict__ wt,
    const float* __restrict__ bias, float* __restrict__ out) {
  __shared__ unsigned short smem[40960];   // 81920 B

  const int tid  = threadIdx.x;
  const int lane = tid & 63;
  const int wid  = tid >> 6;    // 0..3
  const int wn   = wid;         // output row within quad (0..3)
  const int l15  = lane & 15;
  const int lo   = lane >> 4;   // k-octet group

  // XCD-bijective swizzle: grid 1024 = 8 * 128 exactly.
  const int bid0  = blockIdx.x;
  const int bid   = (bid0 & 7) * 128 + (bid0 >> 3);
  const int coutg = bid & 1;               // ((b*16 + ohg)*2 + coutg)
  const int ohg   = (bid >> 1) & 15;
  const int b     = bid >> 5;
  const int cbase = coutg * 128;
  const int oh0   = ohg * 4;               // 0..60 (ohg 15: rows 62,63 masked)

  f32x4 acc[8][4];
  #pragma unroll
  for (int mi = 0; mi < 8; ++mi)
    #pragma unroll
    for (int ni = 0; ni < 4; ++ni)
      acc[mi][ni] = (f32x4){0.f, 0.f, 0.f, 0.f};

  // per-lane LDS read base (bytes); mi/ni terms are static offsets
  const char* sm = (const char*)smem;
  const int af_lane = l15 * 64 + ((lo ^ ((l15 >> 1) & 3)) << 4);

  // persistent staging source pointers
  const size_t xbase = (size_t)b * NH * NW * NCI;
  const unsigned short* xsrc[6];
  #pragma unroll
  for (int i = 0; i < 6; ++i) {
    int e = (wid * 6 + i) * 64 + lane;     // 0..1535
    int o = e & 3, w = (e >> 2) & 63, r = e >> 8;    // r 0..5
    int row = oh0 + r; if (row > 63) row = 63;       // clamp (masked outputs)
    xsrc[i] = xt + xbase + ((size_t)row * NW + w) * NCI
            + ((o ^ ((w >> 1) & 3)) * 8);
  }
  const unsigned short* wsrc2[2];
  #pragma unroll
  for (int i = 0; i < 2; ++i) {
    int e = (wid * 2 + i) * 64 + lane;     // 0..511
    int o = e & 3, co = e >> 2;            // co 0..127
    wsrc2[i] = wt + (size_t)(cbase + co) * NCI + ((o ^ ((co >> 1) & 3)) * 8);
  }

  // stage ws for global tap t into buf t&3: 2 gload/thread
  auto stage_w = [&](int t) {
    unsigned short* dst = smem + 24576 + (t & 3) * 4096;
    const size_t so = (size_t)(t % 9) * NCO * NCI + (t / 9) * 32;
    #pragma unroll
    for (int i = 0; i < 2; ++i)
      gload_lds16(wsrc2[i] + so, dst + ((wid * 2 + i) * 64 + lane) * 8);
  };
  // stage xs chunk c into parity c&1: 6 gload/thread
  auto stage_x = [&](int c) {
    unsigned short* dst = smem + (c & 1) * 12288;
    #pragma unroll
    for (int i = 0; i < 6; ++i)
      gload_lds16(xsrc[i] + c * 32, dst + ((wid * 6 + i) * 64 + lane) * 8);
  };

  // prologue: taps 0,1 + xs chunk 0; full drain once
  stage_w(0);
  stage_w(1);
  stage_x(0);
  asm volatile("s_waitcnt vmcnt(0)" ::: "memory");
  __builtin_amdgcn_s_barrier();
  __builtin_amdgcn_sched_barrier(0);

  for (int t = 0; t < 36; ++t) {
    const int t9 = t % 9, c = t / 9;
    const int kh = t9 / 3, kw = t9 - kh * 3;

    // ---- segment 1: ds reads for tap t (overlap other waves' MFMA(t-1))
    const char* wsp = sm + 49152 + (t & 3) * 8192;
    const char* xsp = sm + (c & 1) * 24576 + (wn + kh) * 4096;
    const int w9  = l15 + kw;
    const int bfl = w9 * 64 + ((lo ^ ((w9 >> 1) & 3)) << 4);
    bf16x8 af[8], bfv[4];
    #pragma unroll
    for (int mi = 0; mi < 8; ++mi)
      af[mi] = *(const bf16x8*)(wsp + mi * 1024 + af_lane);
    #pragma unroll
    for (int ni = 0; ni < 4; ++ni)
      bfv[ni] = *(const bf16x8*)(xsp + ni * 1024 + bfl);

    // ---- stage tap t+2 (and xs chunk c+1 at t9==3)
    if (t + 2 < 36) stage_w(t + 2);
    const bool xstage = (t9 == 3) && (c < 3);
    if (xstage) stage_x(c + 1);

    __builtin_amdgcn_sched_barrier(0);     // pin reads+stages above the wait
    // counted vmcnt: retire stage(t+1); keep just-issued loads in flight
    if (t >= 34) {
      asm volatile("s_waitcnt vmcnt(0)" ::: "memory");
    } else if (xstage || (t9 == 4 && c < 3)) {
      asm volatile("s_waitcnt vmcnt(8)" ::: "memory");
    } else {
      asm volatile("s_waitcnt vmcnt(2)" ::: "memory");
    }
    __builtin_amdgcn_s_barrier();
    asm volatile("s_waitcnt lgkmcnt(0)" ::: "memory");
    __builtin_amdgcn_sched_barrier(0);     // rule 18: no MFMA hoist past wait

    // ---- segment 2: MFMA cluster (operands already in regs)
    __builtin_amdgcn_s_setprio(1);         // T5
    #pragma unroll
    for (int mi = 0; mi < 8; ++mi)
      #pragma unroll
      for (int ni = 0; ni < 4; ++ni)
        acc[mi][ni] = __builtin_amdgcn_mfma_f32_16x16x32_bf16(
            af[mi], bfv[ni], acc[mi][ni], 0, 0, 0);
    __builtin_amdgcn_s_setprio(0);
  }

  // epilogue: D row = lo*4 + reg (cout), col = l15 (ow)
  const int oh = oh0 + wn;
  if (oh < NOH) {
    #pragma unroll
    for (int mi = 0; mi < 8; ++mi) {
      int co0 = cbase + mi * 16 + lo * 4;
      const f32x4 bv = *(const f32x4*)(bias + co0);
      #pragma unroll
      for (int ni = 0; ni < 4; ++ni) {
        int ow = ni * 16 + l15;
        if (ow < NOW) {
          size_t o0 = (((size_t)b * NCO + co0) * NOH + oh) * NOW + ow;
          const size_t cs = (size_t)NOH * NOW;
          out[o0]          = acc[mi][ni][0] + bv[0];
          out[o0 + cs]     = acc[mi][ni][1] + bv[1];
          out[o0 + 2 * cs] = acc[mi][ni][2] + bv[2];
          out[o0 + 3 * cs] = acc[mi][ni][3] + bv[3];
        }
      }
    }
  }
}

// Safety-net: correct fp32 direct conv (used only if ws_size too small)
__global__ __launch_bounds__(256) void conv_naive_kernel(
    const float* __restrict__ x, const float* __restrict__ w,
    const float* __restrict__ bias, float* __restrict__ out) {
  long t = (long)blockIdx.x * 256 + threadIdx.x;
  const long total = (long)NB * NCO * NOH * NOW;
  if (t >= total) return;
  int ow = (int)(t % NOW);
  int oh = (int)((t / NOW) % NOH);
  int co = (int)((t / ((long)NOW * NOH)) % NCO);
  int b  = (int)(t / ((long)NOW * NOH * NCO));
  float acc = bias[co];
  for (int ci = 0; ci < NCI; ++ci) {
    const float* xp = x + (((size_t)b * NCI + ci) * NH + oh) * NW + ow;
    const float* wp = w + ((size_t)co * NCI + ci) * 9;
    #pragma unroll
    for (int kh = 0; kh < 3; ++kh)
      #pragma unroll
      for (int kw = 0; kw < 3; ++kw)
        acc += xp[kh * NW + kw] * wp[kh * 3 + kw];
  }
  out[t] = acc;
}

extern "C" void kernel_launch(void* const* d_in, const int* in_sizes, int n_in,
                              void* d_out, int out_size, void* d_ws, size_t ws_size,
                              hipStream_t stream) {
  const float* x    = (const float*)d_in[0];
  const float* w    = (const float*)d_in[1];
  const float* bias = (const float*)d_in[2];
  float* out        = (float*)d_out;

  const size_t WT_BYTES = (size_t)9 * NCO * NCI * 2;             // 589824
  const size_t XT_BYTES = (size_t)NB * NH * NW * NCI * 2;        // 33554432

  if (ws_size >= WT_BYTES + XT_BYTES) {
    unsigned short* wt = (unsigned short*)d_ws;
    unsigned short* xt = (unsigned short*)((char*)d_ws + WT_BYTES);
    cvt_w_kernel<<<(9 * NCO * 16) / 256, 256, 0, stream>>>(w, wt);
    cvt_x_kernel<<<NB * NH, 256, 0, stream>>>(x, xt);
    conv_mfma_kernel<<<2 * 16 * NB, 256, 0, stream>>>(xt, wt, bias, out);
  } else {
    const long total = (long)NB * NCO * NOH * NOW;
    conv_naive_kernel<<<(int)((total + 255) / 256), 256, 0, stream>>>(x, w, bias, out);
  }
}

// Round 11
// 96.465 us; speedup vs baseline: 1.0473x; 1.0143x over previous
//
#include <hip/hip_runtime.h>

#define NB   32
#define NCI  128
#define NH   64
#define NW   64
#define NCO  256
#define NOH  62
#define NOW  62

typedef __attribute__((ext_vector_type(8))) short bf16x8;           // 8 bf16 (4 VGPRs)
typedef __attribute__((ext_vector_type(8))) unsigned short u16x8;
typedef __attribute__((ext_vector_type(4))) float f32x4;

typedef __attribute__((address_space(1))) const unsigned int glb_u32_t;
typedef __attribute__((address_space(3))) unsigned int lds_u32_t;

// fp32 -> bf16 bits, round-to-nearest-even (finite inputs)
__device__ __forceinline__ unsigned short f2bf(float f) {
  unsigned int u = __float_as_uint(f);
  u = u + 0x7FFFu + ((u >> 16) & 1u);
  return (unsigned short)(u >> 16);
}

__device__ __forceinline__ void gload_lds16(const unsigned short* g, unsigned short* l) {
  __builtin_amdgcn_global_load_lds((glb_u32_t*)g, (lds_u32_t*)l, 16, 0, 0);
}

// x[b][ci][h][w] fp32 -> xt[b][h][w][ci] bf16, transposed through LDS.
__global__ __launch_bounds__(256) void cvt_x_kernel(const float* __restrict__ x,
                                                    unsigned short* __restrict__ xt) {
  __shared__ unsigned short l[64 * 130];   // 16640 B
  const int tid = threadIdx.x;
  const int b = blockIdx.x >> 6, h = blockIdx.x & 63;
  const int w0 = tid & 63, c0 = tid >> 6;
  const float* src = x + ((size_t)b * NCI * NH + h) * NW;
  #pragma unroll
  for (int g = 0; g < 32; ++g) {
    int ci = g * 4 + c0;
    l[w0 * 130 + ci] = f2bf(src[(size_t)ci * (NH * NW) + w0]);
  }
  __syncthreads();
  unsigned short* dst = xt + ((size_t)b * NH + h) * NW * NCI;
  #pragma unroll
  for (int it = 0; it < 4; ++it) {
    int gidx = it * 2048 + tid * 8;
    int w = gidx >> 7, ci0 = gidx & 127;
    const unsigned int* lw = (const unsigned int*)(l + w * 130 + ci0);
    union { u16x8 v; unsigned int u[4]; } t;
    t.u[0] = lw[0]; t.u[1] = lw[1]; t.u[2] = lw[2]; t.u[3] = lw[3];
    *(u16x8*)(dst + w * NCI + ci0) = t.v;
  }
}

// W[co][ci][kh][kw] fp32 -> wt[k][co][ci] bf16, coalesced 16B stores
__global__ __launch_bounds__(256) void cvt_w_kernel(const float* __restrict__ wsrc,
                                                    unsigned short* __restrict__ wt) {
  int t = blockIdx.x * 256 + threadIdx.x;            // 0 .. 9*256*16-1
  int oc = t & 15, co = (t >> 4) & 255, k = t >> 12;
  const float* src = wsrc + ((size_t)co * NCI + oc * 8) * 9 + k;
  u16x8 v;
  #pragma unroll
  for (int j = 0; j < 8; ++j) v[j] = f2bf(src[j * 9]);
  *(u16x8*)(wt + ((size_t)k * NCO + co) * NCI + oc * 8) = v;
}

// Implicit direct conv, bf16 MFMA 16x16x32 — 2-TAP GROUPS (18 barriers).
// Per group k (taps 2k, 2k+1): vmcnt(sel); s_barrier; stage next group's
// ws (+xs at k in {1,6,10}); then barrier-free: readsA, readsB, 64 MFMA —
// the compiler sinks tap-B reads under tap-A MFMAs, keeping the LDS port
// busy during MFMA instead of the per-tap lockstep read-burst that made
// R8-R10 wall = LDS + MFMA (sum, not max).
// Block: 256 thr (4 waves wn 0..3), tile 128 cout x 4 oh x 64 ow;
// wave tile 128co x 64pix (8m x 4n). LDS 80 KB -> 2 blocks/CU:
//   xs: 2 x [6r][64w][4oct][8] (24 KB, parity c&1)    bytes [0, 49152)
//   ws: 2 x [2tap][128co][4oct][8] (16 KB, parity k&1) bytes [49152, 81920)
// Staging AFTER the group barrier (WAR-safe: the overwritten parity buffer
// was last read in group k-1, fenced by this barrier). All waits ~1 group
// (>=2400 cyc) stale -> near-free; vmcnt(6) keeps an in-flight xs stage
// (issued group k-1) alive at k in {2,7,11}, else vmcnt(0).
// Octet swizzle baked into gload_lds SOURCE (LDS dest linear); same XOR on
// read; measured 0 conflicts. xs w-overreads (w up to 65) stay inside the
// 80 KB allocation and feed masked ow>=62 outputs only.
__global__ __launch_bounds__(256, 2) void conv_mfma_kernel(
    const unsigned short* __restrict__ xt, const unsigned short* __restrict__ wt,
    const float* __restrict__ bias, float* __restrict__ out) {
  __shared__ unsigned short smem[40960];   // 81920 B

  const int tid  = threadIdx.x;
  const int lane = tid & 63;
  const int wid  = tid >> 6;    // 0..3
  const int wn   = wid;         // output row within quad (0..3)
  const int l15  = lane & 15;
  const int lo   = lane >> 4;   // k-octet group

  // XCD-bijective swizzle: grid 1024 = 8 * 128 exactly.
  const int bid0  = blockIdx.x;
  const int bid   = (bid0 & 7) * 128 + (bid0 >> 3);
  const int coutg = bid & 1;               // ((b*16 + ohg)*2 + coutg)
  const int ohg   = (bid >> 1) & 15;
  const int b     = bid >> 5;
  const int cbase = coutg * 128;
  const int oh0   = ohg * 4;               // 0..60 (ohg 15: rows 62,63 masked)

  f32x4 acc[8][4];
  #pragma unroll
  for (int mi = 0; mi < 8; ++mi)
    #pragma unroll
    for (int ni = 0; ni < 4; ++ni)
      acc[mi][ni] = (f32x4){0.f, 0.f, 0.f, 0.f};

  // per-lane LDS read base (bytes); mi/ni terms are static offsets
  const char* sm = (const char*)smem;
  const int af_lane = l15 * 64 + ((lo ^ ((l15 >> 1) & 3)) << 4);

  // persistent staging source pointers
  const size_t xbase = (size_t)b * NH * NW * NCI;
  const unsigned short* xsrc[6];
  #pragma unroll
  for (int i = 0; i < 6; ++i) {
    int e = (wid * 6 + i) * 64 + lane;     // 0..1535
    int o = e & 3, w = (e >> 2) & 63, r = e >> 8;    // r 0..5
    int row = oh0 + r; if (row > 63) row = 63;       // clamp (masked outputs)
    xsrc[i] = xt + xbase + ((size_t)row * NW + w) * NCI
            + ((o ^ ((w >> 1) & 3)) * 8);
  }
  const unsigned short* wsrc2[2];
  #pragma unroll
  for (int i = 0; i < 2; ++i) {
    int e = (wid * 2 + i) * 64 + lane;     // 0..511
    int o = e & 3, co = e >> 2;            // co 0..127
    wsrc2[i] = wt + (size_t)(cbase + co) * NCI + ((o ^ ((co >> 1) & 3)) * 8);
  }

  // stage ws for global tap t into group-parity buf, slot t&1: 2 gload/thread
  auto stage_w = [&](int t) {
    unsigned short* dst = smem + 24576 + ((t >> 1) & 1) * 8192 + (t & 1) * 4096;
    const size_t so = (size_t)(t % 9) * NCO * NCI + (t / 9) * 32;
    #pragma unroll
    for (int i = 0; i < 2; ++i)
      gload_lds16(wsrc2[i] + so, dst + ((wid * 2 + i) * 64 + lane) * 8);
  };
  // stage xs chunk c into parity c&1: 6 gload/thread
  auto stage_x = [&](int c) {
    unsigned short* dst = smem + (c & 1) * 12288;
    #pragma unroll
    for (int i = 0; i < 6; ++i)
      gload_lds16(xsrc[i] + c * 32, dst + ((wid * 6 + i) * 64 + lane) * 8);
  };

  // prologue: group 0's ws + xs chunk 0 (retired by k=0's vmcnt(0))
  stage_w(0);
  stage_w(1);
  stage_x(0);

  for (int k = 0; k < 18; ++k) {
    const int ta = 2 * k, tb = ta + 1;
    const int t9a = ta % 9, caa = ta / 9;
    const int t9b = tb % 9, cbb = tb / 9;
    const int kha = t9a / 3, kwa = t9a - kha * 3;
    const int khb = t9b / 3, kwb = t9b - khb * 3;

    // counted wait: retire this group's ws (staged in group k-1); keep an
    // in-flight xs stage (issued group k-1 at k in {2,7,11}) outstanding.
    if (k == 2 || k == 7 || k == 11) {
      asm volatile("s_waitcnt vmcnt(6)" ::: "memory");
    } else {
      asm volatile("s_waitcnt vmcnt(0)" ::: "memory");
    }
    __builtin_amdgcn_s_barrier();
    __builtin_amdgcn_sched_barrier(0);     // no read hoist above the barrier

    // stage next group's ws (+xs): writes the parity last read in group k-1,
    // fenced by the barrier above. Loads stay in flight through this group.
    if (ta + 2 < 36) stage_w(ta + 2);
    if (tb + 2 < 36) stage_w(tb + 2);
    if (k == 1) stage_x(1);
    else if (k == 6) stage_x(2);
    else if (k == 10) stage_x(3);

    // ---- group body: 24 ds_reads + 64 MFMA, compiler-scheduled ----
    const char* wspg = sm + 49152 + (k & 1) * 16384;
    const char* xspa = sm + (caa & 1) * 24576 + (wn + kha) * 4096;
    const char* xspb = sm + (cbb & 1) * 24576 + (wn + khb) * 4096;
    const int w9a = l15 + kwa;
    const int bfla = w9a * 64 + ((lo ^ ((w9a >> 1) & 3)) << 4);
    const int w9b = l15 + kwb;
    const int bflb = w9b * 64 + ((lo ^ ((w9b >> 1) & 3)) << 4);

    bf16x8 afA[8], bfA[4], afB[8], bfB[4];
    #pragma unroll
    for (int mi = 0; mi < 8; ++mi)
      afA[mi] = *(const bf16x8*)(wspg + mi * 1024 + af_lane);
    #pragma unroll
    for (int ni = 0; ni < 4; ++ni)
      bfA[ni] = *(const bf16x8*)(xspa + ni * 1024 + bfla);
    #pragma unroll
    for (int ni = 0; ni < 4; ++ni)
      bfB[ni] = *(const bf16x8*)(xspb + ni * 1024 + bflb);

    __builtin_amdgcn_s_setprio(1);         // T5: group compute at high prio
    #pragma unroll
    for (int mi = 0; mi < 4; ++mi)         // tap A, first half
      #pragma unroll
      for (int ni = 0; ni < 4; ++ni)
        acc[mi][ni] = __builtin_amdgcn_mfma_f32_16x16x32_bf16(
            afA[mi], bfA[ni], acc[mi][ni], 0, 0, 0);

    #pragma unroll
    for (int mi = 0; mi < 8; ++mi)         // tap B af (afA[0..3] now dead)
      afB[mi] = *(const bf16x8*)(wspg + 8192 + mi * 1024 + af_lane);

    #pragma unroll
    for (int mi = 4; mi < 8; ++mi)         // tap A, second half
      #pragma unroll
      for (int ni = 0; ni < 4; ++ni)
        acc[mi][ni] = __builtin_amdgcn_mfma_f32_16x16x32_bf16(
            afA[mi], bfA[ni], acc[mi][ni], 0, 0, 0);

    #pragma unroll
    for (int mi = 0; mi < 8; ++mi)         // tap B
      #pragma unroll
      for (int ni = 0; ni < 4; ++ni)
        acc[mi][ni] = __builtin_amdgcn_mfma_f32_16x16x32_bf16(
            afB[mi], bfB[ni], acc[mi][ni], 0, 0, 0);
    __builtin_amdgcn_s_setprio(0);
  }

  // epilogue: D row = lo*4 + reg (cout), col = l15 (ow)
  const int oh = oh0 + wn;
  if (oh < NOH) {
    #pragma unroll
    for (int mi = 0; mi < 8; ++mi) {
      int co0 = cbase + mi * 16 + lo * 4;
      const f32x4 bv = *(const f32x4*)(bias + co0);
      #pragma unroll
      for (int ni = 0; ni < 4; ++ni) {
        int ow = ni * 16 + l15;
        if (ow < NOW) {
          size_t o0 = (((size_t)b * NCO + co0) * NOH + oh) * NOW + ow;
          const size_t cs = (size_t)NOH * NOW;
          out[o0]          = acc[mi][ni][0] + bv[0];
          out[o0 + cs]     = acc[mi][ni][1] + bv[1];
          out[o0 + 2 * cs] = acc[mi][ni][2] + bv[2];
          out[o0 + 3 * cs] = acc[mi][ni][3] + bv[3];
        }
      }
    }
  }
}

// Safety-net: correct fp32 direct conv (used only if ws_size too small)
__global__ __launch_bounds__(256) void conv_naive_kernel(
    const float* __restrict__ x, const float* __restrict__ w,
    const float* __restrict__ bias, float* __restrict__ out) {
  long t = (long)blockIdx.x * 256 + threadIdx.x;
  const long total = (long)NB * NCO * NOH * NOW;
  if (t >= total) return;
  int ow = (int)(t % NOW);
  int oh = (int)((t / NOW) % NOH);
  int co = (int)((t / ((long)NOW * NOH)) % NCO);
  int b  = (int)(t / ((long)NOW * NOH * NCO));
  float acc = bias[co];
  for (int ci = 0; ci < NCI; ++ci) {
    const float* xp = x + (((size_t)b * NCI + ci) * NH + oh) * NW + ow;
    const float* wp = w + ((size_t)co * NCI + ci) * 9;
    #pragma unroll
    for (int kh = 0; kh < 3; ++kh)
      #pragma unroll
      for (int kw = 0; kw < 3; ++kw)
        acc += xp[kh * NW + kw] * wp[kh * 3 + kw];
  }
  out[t] = acc;
}

extern "C" void kernel_launch(void* const* d_in, const int* in_sizes, int n_in,
                              void* d_out, int out_size, void* d_ws, size_t ws_size,
                              hipStream_t stream) {
  const float* x    = (const float*)d_in[0];
  const float* w    = (const float*)d_in[1];
  const float* bias = (const float*)d_in[2];
  float* out        = (float*)d_out;

  const size_t WT_BYTES = (size_t)9 * NCO * NCI * 2;             // 589824
  const size_t XT_BYTES = (size_t)NB * NH * NW * NCI * 2;        // 33554432

  if (ws_size >= WT_BYTES + XT_BYTES) {
    unsigned short* wt = (unsigned short*)d_ws;
    unsigned short* xt = (unsigned short*)((char*)d_ws + WT_BYTES);
    cvt_w_kernel<<<(9 * NCO * 16) / 256, 256, 0, stream>>>(w, wt);
    cvt_x_kernel<<<NB * NH, 256, 0, stream>>>(x, xt);
    conv_mfma_kernel<<<2 * 16 * NB, 256, 0, stream>>>(xt, wt, bias, out);
  } else {
    const long total = (long)NB * NCO * NOH * NOW;
    conv_naive_kernel<<<(int)((total + 255) / 256), 256, 0, stream>>>(x, w, bias, out);
  }
}

// Round 12
// 96.116 us; speedup vs baseline: 1.0511x; 1.0036x over previous
//
#include <hip/hip_runtime.h>

#define NB   32
#define NCI  128
#define NH   64
#define NW   64
#define NCO  256
#define NOH  62
#define NOW  62

typedef __attribute__((ext_vector_type(8))) short bf16x8;           // 8 bf16 (4 VGPRs)
typedef __attribute__((ext_vector_type(8))) unsigned short u16x8;
typedef __attribute__((ext_vector_type(4))) float f32x4;

typedef __attribute__((address_space(1))) const unsigned int glb_u32_t;
typedef __attribute__((address_space(3))) unsigned int lds_u32_t;

// fp32 -> bf16 bits, round-to-nearest-even (finite inputs)
__device__ __forceinline__ unsigned short f2bf(float f) {
  unsigned int u = __float_as_uint(f);
  u = u + 0x7FFFu + ((u >> 16) & 1u);
  return (unsigned short)(u >> 16);
}

__device__ __forceinline__ void gload_lds16(const unsigned short* g, unsigned short* l) {
  __builtin_amdgcn_global_load_lds((glb_u32_t*)g, (lds_u32_t*)l, 16, 0, 0);
}

// x[b][ci][h][w] fp32 -> xt[b][h][w][ci] bf16, transposed through LDS.
__global__ __launch_bounds__(256) void cvt_x_kernel(const float* __restrict__ x,
                                                    unsigned short* __restrict__ xt) {
  __shared__ unsigned short l[64 * 130];   // 16640 B
  const int tid = threadIdx.x;
  const int b = blockIdx.x >> 6, h = blockIdx.x & 63;
  const int w0 = tid & 63, c0 = tid >> 6;
  const float* src = x + ((size_t)b * NCI * NH + h) * NW;
  #pragma unroll
  for (int g = 0; g < 32; ++g) {
    int ci = g * 4 + c0;
    l[w0 * 130 + ci] = f2bf(src[(size_t)ci * (NH * NW) + w0]);
  }
  __syncthreads();
  unsigned short* dst = xt + ((size_t)b * NH + h) * NW * NCI;
  #pragma unroll
  for (int it = 0; it < 4; ++it) {
    int gidx = it * 2048 + tid * 8;
    int w = gidx >> 7, ci0 = gidx & 127;
    const unsigned int* lw = (const unsigned int*)(l + w * 130 + ci0);
    union { u16x8 v; unsigned int u[4]; } t;
    t.u[0] = lw[0]; t.u[1] = lw[1]; t.u[2] = lw[2]; t.u[3] = lw[3];
    *(u16x8*)(dst + w * NCI + ci0) = t.v;
  }
}

// W[co][ci][kh][kw] fp32 -> wt[k][co][ci] bf16, coalesced 16B stores
__global__ __launch_bounds__(256) void cvt_w_kernel(const float* __restrict__ wsrc,
                                                    unsigned short* __restrict__ wt) {
  int t = blockIdx.x * 256 + threadIdx.x;            // 0 .. 9*256*16-1
  int oc = t & 15, co = (t >> 4) & 255, k = t >> 12;
  const float* src = wsrc + ((size_t)co * NCI + oc * 8) * 9 + k;
  u16x8 v;
  #pragma unroll
  for (int j = 0; j < 8; ++j) v[j] = f2bf(src[j * 9]);
  *(u16x8*)(wt + ((size_t)k * NCO + co) * NCI + oc * 8) = v;
}

// Implicit direct conv, bf16 MFMA 16x16x32 — REGISTER-PREFETCH pipeline.
// R11's counter fit proved wall = LDS + MFMA (sum, zero overlap): each tap's
// fragments were read in the same barrier span that consumed them. Now the
// reads for tap t+1 are interleaved INTO tap t's MFMA cluster (cur/nxt frag
// ping-pong), so the lgkmcnt(0) at each tap top waits on reads issued a full
// MFMA cluster earlier, and the LDS port runs during MFMA -> wall -> max.
// Block: 256 thr (4 waves wn 0..3), tile 128 cout x 4 oh x 64 ow;
// wave tile 128co x 64pix (8m x 4n). 36 taps t = c*9 + t9.
// LDS exactly 80 KB -> 2 blocks/CU:
//   xs: 2 x [6r][64w][4oct][8] (24 KB, parity c&1)  bytes [0, 49152)
//   ws: 4 x [128co][4oct][8]   (8 KB, slot t&3)     bytes [49152, 81920)
// ws staging depth 3 (stage t+3 at tap t): slot (t+1) staged at t-2, vmcnt-
// retired at end of t-1, barrier-fenced before its prefetch-reads at tap t.
// WAR ring-4: stage(t+3) overwrites tap t-1's slot; those reads completed by
// each wave's lgkm at tap t-1 top, which precedes its end-of-(t-1) barrier.
// vmcnt at tap end: 2 (retire stage(t+2), keep stage(t+3)); 8 at the two
// taps following an xs stage (keep xs in flight); 0 only in the tail.
// Octet swizzle baked into gload_lds SOURCE (LDS dest linear); same XOR on
// read; measured 0 conflicts. xs w-overreads (w up to 65) stay inside the
// 80 KB allocation and feed masked ow>=62 outputs only.
__global__ __launch_bounds__(256, 2) void conv_mfma_kernel(
    const unsigned short* __restrict__ xt, const unsigned short* __restrict__ wt,
    const float* __restrict__ bias, float* __restrict__ out) {
  __shared__ unsigned short smem[40960];   // 81920 B

  const int tid  = threadIdx.x;
  const int lane = tid & 63;
  const int wid  = tid >> 6;    // 0..3
  const int wn   = wid;         // output row within quad (0..3)
  const int l15  = lane & 15;
  const int lo   = lane >> 4;   // k-octet group

  // XCD-bijective swizzle: grid 1024 = 8 * 128 exactly.
  const int bid0  = blockIdx.x;
  const int bid   = (bid0 & 7) * 128 + (bid0 >> 3);
  const int coutg = bid & 1;               // ((b*16 + ohg)*2 + coutg)
  const int ohg   = (bid >> 1) & 15;
  const int b     = bid >> 5;
  const int cbase = coutg * 128;
  const int oh0   = ohg * 4;               // 0..60 (ohg 15: rows 62,63 masked)

  f32x4 acc[8][4];
  #pragma unroll
  for (int mi = 0; mi < 8; ++mi)
    #pragma unroll
    for (int ni = 0; ni < 4; ++ni)
      acc[mi][ni] = (f32x4){0.f, 0.f, 0.f, 0.f};

  // per-lane LDS read base (bytes); mi/ni terms are static offsets
  const char* sm = (const char*)smem;
  const int af_lane = l15 * 64 + ((lo ^ ((l15 >> 1) & 3)) << 4);

  // persistent staging source pointers
  const size_t xbase = (size_t)b * NH * NW * NCI;
  const unsigned short* xsrc[6];
  #pragma unroll
  for (int i = 0; i < 6; ++i) {
    int e = (wid * 6 + i) * 64 + lane;     // 0..1535
    int o = e & 3, w = (e >> 2) & 63, r = e >> 8;    // r 0..5
    int row = oh0 + r; if (row > 63) row = 63;       // clamp (masked outputs)
    xsrc[i] = xt + xbase + ((size_t)row * NW + w) * NCI
            + ((o ^ ((w >> 1) & 3)) * 8);
  }
  const unsigned short* wsrc2[2];
  #pragma unroll
  for (int i = 0; i < 2; ++i) {
    int e = (wid * 2 + i) * 64 + lane;     // 0..511
    int o = e & 3, co = e >> 2;            // co 0..127
    wsrc2[i] = wt + (size_t)(cbase + co) * NCI + ((o ^ ((co >> 1) & 3)) * 8);
  }

  // stage ws for global tap t into slot t&3: 2 gload/thread
  auto stage_w = [&](int t) {
    unsigned short* dst = smem + 24576 + (t & 3) * 4096;
    const size_t so = (size_t)(t % 9) * NCO * NCI + (t / 9) * 32;
    #pragma unroll
    for (int i = 0; i < 2; ++i)
      gload_lds16(wsrc2[i] + so, dst + ((wid * 2 + i) * 64 + lane) * 8);
  };
  // stage xs chunk c into parity c&1: 6 gload/thread
  auto stage_x = [&](int c) {
    unsigned short* dst = smem + (c & 1) * 12288;
    #pragma unroll
    for (int i = 0; i < 6; ++i)
      gload_lds16(xsrc[i] + c * 32, dst + ((wid * 6 + i) * 64 + lane) * 8);
  };

  bf16x8 afA[8], bfA[4], afB[8], bfB[4];

  // read frags for tap t into (af, bf) — used only for the initial fill
  auto read_frags = [&](bf16x8 (&af)[8], bf16x8 (&bf)[4], int t) {
    const char* wsp = sm + 49152 + (t & 3) * 8192;
    const int t9 = t % 9, c = t / 9, kh = t9 / 3, kw = t9 - kh * 3;
    const char* xsp = sm + (c & 1) * 24576 + (wn + kh) * 4096;
    const int w9 = l15 + kw;
    const int bfl = w9 * 64 + ((lo ^ ((w9 >> 1) & 3)) << 4);
    #pragma unroll
    for (int mi = 0; mi < 8; ++mi)
      af[mi] = *(const bf16x8*)(wsp + mi * 1024 + af_lane);
    #pragma unroll
    for (int ni = 0; ni < 4; ++ni)
      bf[ni] = *(const bf16x8*)(xsp + ni * 1024 + bfl);
  };

  // MFMA cluster for cur frags, with tap tn's reads interleaved into nxt
  auto tap_mfma = [&](bf16x8 (&caf)[8], bf16x8 (&cbf)[4],
                      bf16x8 (&naf)[8], bf16x8 (&nbf)[4], int tn, bool pf) {
    const char* wspn = sm + 49152 + (tn & 3) * 8192;
    const int t9 = tn % 9, cc = tn / 9, khn = t9 / 3, kwn = t9 - khn * 3;
    const char* xspn = sm + (cc & 1) * 24576 + (wn + khn) * 4096;
    const int w9 = l15 + kwn;
    const int bfln = w9 * 64 + ((lo ^ ((w9 >> 1) & 3)) << 4);

    asm volatile("s_waitcnt lgkmcnt(0)" ::: "memory");  // cur frags landed
    __builtin_amdgcn_sched_barrier(0);                  // rule 18
    __builtin_amdgcn_s_setprio(1);                      // T5
    #pragma unroll
    for (int mi = 0; mi < 8; ++mi) {
      #pragma unroll
      for (int ni = 0; ni < 4; ++ni)
        acc[mi][ni] = __builtin_amdgcn_mfma_f32_16x16x32_bf16(
            caf[mi], cbf[ni], acc[mi][ni], 0, 0, 0);
      if (pf) {                       // prefetch reads ride under the MFMAs
        if (mi < 4) {
          naf[2 * mi]     = *(const bf16x8*)(wspn + (2 * mi) * 1024 + af_lane);
          naf[2 * mi + 1] = *(const bf16x8*)(wspn + (2 * mi + 1) * 1024 + af_lane);
        } else if (mi < 6) {
          nbf[2 * (mi - 4)]     = *(const bf16x8*)(xspn + (2 * (mi - 4)) * 1024 + bfln);
          nbf[2 * (mi - 4) + 1] = *(const bf16x8*)(xspn + (2 * (mi - 4) + 1) * 1024 + bfln);
        }
      }
    }
    __builtin_amdgcn_s_setprio(0);
  };

  // prologue: taps 0,1,2 + xs chunk 0; full drain; initial frag fill (tap 0)
  stage_w(0);
  stage_w(1);
  stage_w(2);
  stage_x(0);
  asm volatile("s_waitcnt vmcnt(0)" ::: "memory");
  __builtin_amdgcn_s_barrier();
  __builtin_amdgcn_sched_barrier(0);
  read_frags(afA, bfA, 0);

  for (int j = 0; j < 9; ++j) {
    const int t0 = 4 * j;
    const bool xst = (j == 1 || j == 3 || j == 5);

    // pos 0: cur A (tap t0), prefetch B (tap t0+1)
    if (t0 + 3 <= 35) stage_w(t0 + 3);
    if (xst) stage_x(j / 2 + 1);             // chunks 1,2,3 at j=1,3,5
    tap_mfma(afA, bfA, afB, bfB, t0 + 1, true);
    if (xst) { asm volatile("s_waitcnt vmcnt(8)" ::: "memory"); }
    else     { asm volatile("s_waitcnt vmcnt(2)" ::: "memory"); }
    __builtin_amdgcn_s_barrier();
    __builtin_amdgcn_sched_barrier(0);

    // pos 1: cur B (tap t0+1), prefetch A (tap t0+2)
    if (t0 + 4 <= 35) stage_w(t0 + 4);
    tap_mfma(afB, bfB, afA, bfA, t0 + 2, true);
    if (xst)            { asm volatile("s_waitcnt vmcnt(8)" ::: "memory"); }
    else if (t0 == 32)  { asm volatile("s_waitcnt vmcnt(0)" ::: "memory"); }
    else                { asm volatile("s_waitcnt vmcnt(2)" ::: "memory"); }
    __builtin_amdgcn_s_barrier();
    __builtin_amdgcn_sched_barrier(0);

    // pos 2: cur A (tap t0+2), prefetch B (tap t0+3)
    if (t0 + 5 <= 35) stage_w(t0 + 5);
    tap_mfma(afA, bfA, afB, bfB, t0 + 3, true);
    if (t0 == 32) { asm volatile("s_waitcnt vmcnt(0)" ::: "memory"); }
    else          { asm volatile("s_waitcnt vmcnt(2)" ::: "memory"); }
    __builtin_amdgcn_s_barrier();
    __builtin_amdgcn_sched_barrier(0);

    // pos 3: cur B (tap t0+3), prefetch A (tap t0+4) unless last
    if (t0 + 6 <= 35) stage_w(t0 + 6);
    tap_mfma(afB, bfB, afA, bfA, t0 + 4, j < 8);
    if (j < 8) {
      asm volatile("s_waitcnt vmcnt(2)" ::: "memory");
      __builtin_amdgcn_s_barrier();
      __builtin_amdgcn_sched_barrier(0);
    }
  }

  // epilogue: D row = lo*4 + reg (cout), col = l15 (ow)
  const int oh = oh0 + wn;
  if (oh < NOH) {
    #pragma unroll
    for (int mi = 0; mi < 8; ++mi) {
      int co0 = cbase + mi * 16 + lo * 4;
      const f32x4 bv = *(const f32x4*)(bias + co0);
      #pragma unroll
      for (int ni = 0; ni < 4; ++ni) {
        int ow = ni * 16 + l15;
        if (ow < NOW) {
          size_t o0 = (((size_t)b * NCO + co0) * NOH + oh) * NOW + ow;
          const size_t cs = (size_t)NOH * NOW;
          out[o0]          = acc[mi][ni][0] + bv[0];
          out[o0 + cs]     = acc[mi][ni][1] + bv[1];
          out[o0 + 2 * cs] = acc[mi][ni][2] + bv[2];
          out[o0 + 3 * cs] = acc[mi][ni][3] + bv[3];
        }
      }
    }
  }
}

// Safety-net: correct fp32 direct conv (used only if ws_size too small)
__global__ __launch_bounds__(256) void conv_naive_kernel(
    const float* __restrict__ x, const float* __restrict__ w,
    const float* __restrict__ bias, float* __restrict__ out) {
  long t = (long)blockIdx.x * 256 + threadIdx.x;
  const long total = (long)NB * NCO * NOH * NOW;
  if (t >= total) return;
  int ow = (int)(t % NOW);
  int oh = (int)((t / NOW) % NOH);
  int co = (int)((t / ((long)NOW * NOH)) % NCO);
  int b  = (int)(t / ((long)NOW * NOH * NCO));
  float acc = bias[co];
  for (int ci = 0; ci < NCI; ++ci) {
    const float* xp = x + (((size_t)b * NCI + ci) * NH + oh) * NW + ow;
    const float* wp = w + ((size_t)co * NCI + ci) * 9;
    #pragma unroll
    for (int kh = 0; kh < 3; ++kh)
      #pragma unroll
      for (int kw = 0; kw < 3; ++kw)
        acc += xp[kh * NW + kw] * wp[kh * 3 + kw];
  }
  out[t] = acc;
}

extern "C" void kernel_launch(void* const* d_in, const int* in_sizes, int n_in,
                              void* d_out, int out_size, void* d_ws, size_t ws_size,
                              hipStream_t stream) {
  const float* x    = (const float*)d_in[0];
  const float* w    = (const float*)d_in[1];
  const float* bias = (const float*)d_in[2];
  float* out        = (float*)d_out;

  const size_t WT_BYTES = (size_t)9 * NCO * NCI * 2;             // 589824
  const size_t XT_BYTES = (size_t)NB * NH * NW * NCI * 2;        // 33554432

  if (ws_size >= WT_BYTES + XT_BYTES) {
    unsigned short* wt = (unsigned short*)d_ws;
    unsigned short* xt = (unsigned short*)((char*)d_ws + WT_BYTES);
    cvt_w_kernel<<<(9 * NCO * 16) / 256, 256, 0, stream>>>(w, wt);
    cvt_x_kernel<<<NB * NH, 256, 0, stream>>>(x, xt);
    conv_mfma_kernel<<<2 * 16 * NB, 256, 0, stream>>>(xt, wt, bias, out);
  } else {
    const long total = (long)NB * NCO * NOH * NOW;
    conv_naive_kernel<<<(int)((total + 255) / 256), 256, 0, stream>>>(x, w, bias, out);
  }
}

// Round 13
// 95.080 us; speedup vs baseline: 1.0626x; 1.0109x over previous
//
#include <hip/hip_runtime.h>

#define NB   32
#define NCI  128
#define NH   64
#define NW   64
#define NCO  256
#define NOH  62
#define NOW  62

typedef __attribute__((ext_vector_type(8))) short bf16x8;           // 8 bf16 (4 VGPRs)
typedef __attribute__((ext_vector_type(8))) unsigned short u16x8;
typedef __attribute__((ext_vector_type(4))) float f32x4;

typedef __attribute__((address_space(1))) const unsigned int glb_u32_t;
typedef __attribute__((address_space(3))) unsigned int lds_u32_t;

// fp32 -> bf16 bits, round-to-nearest-even (finite inputs)
__device__ __forceinline__ unsigned short f2bf(float f) {
  unsigned int u = __float_as_uint(f);
  u = u + 0x7FFFu + ((u >> 16) & 1u);
  return (unsigned short)(u >> 16);
}

__device__ __forceinline__ void gload_lds16(const unsigned short* g, unsigned short* l) {
  __builtin_amdgcn_global_load_lds((glb_u32_t*)g, (lds_u32_t*)l, 16, 0, 0);
}

// x[b][ci][h][w] fp32 -> xt[b][h][w][ci] bf16, transposed through LDS.
__global__ __launch_bounds__(256) void cvt_x_kernel(const float* __restrict__ x,
                                                    unsigned short* __restrict__ xt) {
  __shared__ unsigned short l[64 * 130];   // 16640 B
  const int tid = threadIdx.x;
  const int b = blockIdx.x >> 6, h = blockIdx.x & 63;
  const int w0 = tid & 63, c0 = tid >> 6;
  const float* src = x + ((size_t)b * NCI * NH + h) * NW;
  #pragma unroll
  for (int g = 0; g < 32; ++g) {
    int ci = g * 4 + c0;
    l[w0 * 130 + ci] = f2bf(src[(size_t)ci * (NH * NW) + w0]);
  }
  __syncthreads();
  unsigned short* dst = xt + ((size_t)b * NH + h) * NW * NCI;
  #pragma unroll
  for (int it = 0; it < 4; ++it) {
    int gidx = it * 2048 + tid * 8;
    int w = gidx >> 7, ci0 = gidx & 127;
    const unsigned int* lw = (const unsigned int*)(l + w * 130 + ci0);
    union { u16x8 v; unsigned int u[4]; } t;
    t.u[0] = lw[0]; t.u[1] = lw[1]; t.u[2] = lw[2]; t.u[3] = lw[3];
    *(u16x8*)(dst + w * NCI + ci0) = t.v;
  }
}

// W[co][ci][kh][kw] fp32 -> wt[k][co][ci] bf16, coalesced 16B stores
__global__ __launch_bounds__(256) void cvt_w_kernel(const float* __restrict__ wsrc,
                                                    unsigned short* __restrict__ wt) {
  int t = blockIdx.x * 256 + threadIdx.x;            // 0 .. 9*256*16-1
  int oc = t & 15, co = (t >> 4) & 255, k = t >> 12;
  const float* src = wsrc + ((size_t)co * NCI + oc * 8) * 9 + k;
  u16x8 v;
  #pragma unroll
  for (int j = 0; j < 8; ++j) v[j] = f2bf(src[j * 9]);
  *(u16x8*)(wt + ((size_t)k * NCO + co) * NCI + oc * 8) = v;
}

// Implicit direct conv, bf16 MFMA 16x16x32 — HALF-TAP register pipeline.
// R12's prefetch was silently serialized by the register allocator (96 VGPR
// of frag dbuf + 128 acc > 256 budget -> compiler sank reads next to uses;
// VGPR_Count pinned at 128, wall = LDS + MFMA exactly). This version halves
// the frag footprint (afX/afY/bfC/bfD = 64 VGPR) so the interleave survives:
//   half0: 16 MFMA (afX x bfc -> acc[0..3])  ||  read afY = af[4:7](t)
//   half1: 16 MFMA (afY x bfc -> acc[4..7])  ||  read afX = af[0:3](t+1),
//                                                bfn = bf(t+1)
// Each lgkm(0) waits on reads issued a full MFMA cluster earlier.
// Block: 256 thr (4 waves wn 0..3), tile 128 cout x 4 oh x 64 ow;
// wave tile 128co x 64pix (8m x 4n). 36 taps t = c*9 + t9. LDS 80 KB:
//   xs: 2 x [6r][64w][4oct][8] (24 KB, parity c&1)  bytes [0, 49152)
//   ws: 4 x [128co][4oct][8]   (8 KB, slot t&3)     bytes [49152, 81920)
// ws staging depth 3 (stage t+3 at tap t top). WAR on slot (t+3)&3=(t-1)&3:
// its last reads (afY at t-1 half0 / prefetch at t-2 half1) complete before
// each wave's half1 lgkm at t-1, which precedes the end-of-(t-1) barrier;
// stage_w(t+3) is issued after that barrier. xs chunk c+1 staged at t9==5,
// written parity last read at tap 9c-2 (7 barriers earlier), vmcnt-retired
// by end of 9c+7, first read at 9c+8 half1 (prefetch for tap 9c+9).
// vmcnt at tap end: 2 normal; 8 at t9 in {5,6} (keep xs 6 + newest ws 2 in
// flight, retire older); 0 at t>=33. Octet swizzle baked into gload_lds
// SOURCE (LDS dest linear); same XOR on read; 0 conflicts measured. xs
// w-overreads (w up to 65) stay in-allocation, feed masked ow>=62 only.
__global__ __launch_bounds__(256, 2) void conv_mfma_kernel(
    const unsigned short* __restrict__ xt, const unsigned short* __restrict__ wt,
    const float* __restrict__ bias, float* __restrict__ out) {
  __shared__ unsigned short smem[40960];   // 81920 B

  const int tid  = threadIdx.x;
  const int lane = tid & 63;
  const int wid  = tid >> 6;    // 0..3
  const int wn   = wid;         // output row within quad (0..3)
  const int l15  = lane & 15;
  const int lo   = lane >> 4;   // k-octet group

  // XCD-bijective swizzle: grid 1024 = 8 * 128 exactly.
  const int bid0  = blockIdx.x;
  const int bid   = (bid0 & 7) * 128 + (bid0 >> 3);
  const int coutg = bid & 1;               // ((b*16 + ohg)*2 + coutg)
  const int ohg   = (bid >> 1) & 15;
  const int b     = bid >> 5;
  const int cbase = coutg * 128;
  const int oh0   = ohg * 4;               // 0..60 (ohg 15: rows 62,63 masked)

  f32x4 acc[8][4];
  #pragma unroll
  for (int mi = 0; mi < 8; ++mi)
    #pragma unroll
    for (int ni = 0; ni < 4; ++ni)
      acc[mi][ni] = (f32x4){0.f, 0.f, 0.f, 0.f};

  // per-lane LDS read base (bytes); mi/ni terms are static offsets
  const char* sm = (const char*)smem;
  const int af_lane = l15 * 64 + ((lo ^ ((l15 >> 1) & 3)) << 4);

  // persistent staging source pointers
  const size_t xbase = (size_t)b * NH * NW * NCI;
  const unsigned short* xsrc[6];
  #pragma unroll
  for (int i = 0; i < 6; ++i) {
    int e = (wid * 6 + i) * 64 + lane;     // 0..1535
    int o = e & 3, w = (e >> 2) & 63, r = e >> 8;    // r 0..5
    int row = oh0 + r; if (row > 63) row = 63;       // clamp (masked outputs)
    xsrc[i] = xt + xbase + ((size_t)row * NW + w) * NCI
            + ((o ^ ((w >> 1) & 3)) * 8);
  }
  const unsigned short* wsrc2[2];
  #pragma unroll
  for (int i = 0; i < 2; ++i) {
    int e = (wid * 2 + i) * 64 + lane;     // 0..511
    int o = e & 3, co = e >> 2;            // co 0..127
    wsrc2[i] = wt + (size_t)(cbase + co) * NCI + ((o ^ ((co >> 1) & 3)) * 8);
  }

  // stage ws for global tap t into slot t&3: 2 gload/thread
  auto stage_w = [&](int t) {
    unsigned short* dst = smem + 24576 + (t & 3) * 4096;
    const size_t so = (size_t)(t % 9) * NCO * NCI + (t / 9) * 32;
    #pragma unroll
    for (int i = 0; i < 2; ++i)
      gload_lds16(wsrc2[i] + so, dst + ((wid * 2 + i) * 64 + lane) * 8);
  };
  // stage xs chunk c into parity c&1: 6 gload/thread
  auto stage_x = [&](int c) {
    unsigned short* dst = smem + (c & 1) * 12288;
    #pragma unroll
    for (int i = 0; i < 6; ++i)
      gload_lds16(xsrc[i] + c * 32, dst + ((wid * 6 + i) * 64 + lane) * 8);
  };

  bf16x8 afX[4], afY[4], bfC[4], bfD[4];

  // one tap: two 16-MFMA halves with interleaved reads; bfc = this tap's
  // B-frags (already loaded), bfn = next tap's (written by the prefetch).
  auto tap_body = [&](int t, bf16x8 (&bfc)[4], bf16x8 (&bfn)[4], bool pf) {
    const int t9 = t % 9, c = t / 9;
    const bool xst = (t9 == 5) && (c < 3);
    if (t + 3 < 36) stage_w(t + 3);
    if (xst) stage_x(c + 1);

    const char* wsp = sm + 49152 + (t & 3) * 8192;      // this tap's ws slot
    const int  tn   = t + 1;
    const char* wspn = sm + 49152 + (tn & 3) * 8192;    // next tap's ws slot
    const int  tn9 = tn % 9, cn = tn / 9;
    const int  khn = tn9 / 3, kwn = tn9 - khn * 3;
    const char* xspn = sm + (cn & 1) * 24576 + (wn + khn) * 4096;
    const int  w9n  = l15 + kwn;
    const int  bfln = w9n * 64 + ((lo ^ ((w9n >> 1) & 3)) << 4);

    // ---- half 0: acc[0..3] += afX x bfc  ||  afY <- af[4:7](t)
    asm volatile("s_waitcnt lgkmcnt(0)" ::: "memory");
    __builtin_amdgcn_sched_barrier(0);
    __builtin_amdgcn_s_setprio(1);
    #pragma unroll
    for (int ni = 0; ni < 4; ++ni)
      acc[0][ni] = __builtin_amdgcn_mfma_f32_16x16x32_bf16(afX[0], bfc[ni], acc[0][ni], 0, 0, 0);
    afY[0] = *(const bf16x8*)(wsp + 4 * 1024 + af_lane);
    afY[1] = *(const bf16x8*)(wsp + 5 * 1024 + af_lane);
    #pragma unroll
    for (int ni = 0; ni < 4; ++ni)
      acc[1][ni] = __builtin_amdgcn_mfma_f32_16x16x32_bf16(afX[1], bfc[ni], acc[1][ni], 0, 0, 0);
    afY[2] = *(const bf16x8*)(wsp + 6 * 1024 + af_lane);
    afY[3] = *(const bf16x8*)(wsp + 7 * 1024 + af_lane);
    #pragma unroll
    for (int ni = 0; ni < 4; ++ni)
      acc[2][ni] = __builtin_amdgcn_mfma_f32_16x16x32_bf16(afX[2], bfc[ni], acc[2][ni], 0, 0, 0);
    #pragma unroll
    for (int ni = 0; ni < 4; ++ni)
      acc[3][ni] = __builtin_amdgcn_mfma_f32_16x16x32_bf16(afX[3], bfc[ni], acc[3][ni], 0, 0, 0);
    __builtin_amdgcn_s_setprio(0);

    // ---- half 1: acc[4..7] += afY x bfc  ||  afX <- af[0:3](t+1), bfn <- bf(t+1)
    asm volatile("s_waitcnt lgkmcnt(0)" ::: "memory");
    __builtin_amdgcn_sched_barrier(0);
    __builtin_amdgcn_s_setprio(1);
    #pragma unroll
    for (int ni = 0; ni < 4; ++ni)
      acc[4][ni] = __builtin_amdgcn_mfma_f32_16x16x32_bf16(afY[0], bfc[ni], acc[4][ni], 0, 0, 0);
    if (pf) {
      afX[0] = *(const bf16x8*)(wspn + 0 * 1024 + af_lane);
      afX[1] = *(const bf16x8*)(wspn + 1 * 1024 + af_lane);
    }
    #pragma unroll
    for (int ni = 0; ni < 4; ++ni)
      acc[5][ni] = __builtin_amdgcn_mfma_f32_16x16x32_bf16(afY[1], bfc[ni], acc[5][ni], 0, 0, 0);
    if (pf) {
      afX[2] = *(const bf16x8*)(wspn + 2 * 1024 + af_lane);
      afX[3] = *(const bf16x8*)(wspn + 3 * 1024 + af_lane);
    }
    #pragma unroll
    for (int ni = 0; ni < 4; ++ni)
      acc[6][ni] = __builtin_amdgcn_mfma_f32_16x16x32_bf16(afY[2], bfc[ni], acc[6][ni], 0, 0, 0);
    if (pf) {
      #pragma unroll
      for (int i = 0; i < 4; ++i)
        bfn[i] = *(const bf16x8*)(xspn + i * 1024 + bfln);
    }
    #pragma unroll
    for (int ni = 0; ni < 4; ++ni)
      acc[7][ni] = __builtin_amdgcn_mfma_f32_16x16x32_bf16(afY[3], bfc[ni], acc[7][ni], 0, 0, 0);
    __builtin_amdgcn_s_setprio(0);

    // ---- tap end: counted vmcnt + barrier
    if (t >= 33) {
      asm volatile("s_waitcnt vmcnt(0)" ::: "memory");
    } else if ((t9 == 5 || t9 == 6) && c < 3) {
      asm volatile("s_waitcnt vmcnt(8)" ::: "memory");
    } else {
      asm volatile("s_waitcnt vmcnt(2)" ::: "memory");
    }
    __builtin_amdgcn_s_barrier();
    __builtin_amdgcn_sched_barrier(0);
  };

  // prologue: ws slots 0,1,2 + xs chunk 0; drain; initial frag fill (tap 0)
  stage_w(0);
  stage_w(1);
  stage_w(2);
  stage_x(0);
  asm volatile("s_waitcnt vmcnt(0)" ::: "memory");
  __builtin_amdgcn_s_barrier();
  __builtin_amdgcn_sched_barrier(0);
  {
    const char* wsp0 = sm + 49152;
    #pragma unroll
    for (int i = 0; i < 4; ++i)
      afX[i] = *(const bf16x8*)(wsp0 + i * 1024 + af_lane);
    const char* xsp0 = sm + wn * 4096;       // t=0: c=0, kh=0
    #pragma unroll
    for (int i = 0; i < 4; ++i)              // kw=0: bfl == af_lane formula
      bfC[i] = *(const bf16x8*)(xsp0 + i * 1024 + af_lane);
  }

  for (int j = 0; j < 9; ++j) {
    const int t0 = 4 * j;
    tap_body(t0 + 0, bfC, bfD, true);
    tap_body(t0 + 1, bfD, bfC, true);
    tap_body(t0 + 2, bfC, bfD, true);
    tap_body(t0 + 3, bfD, bfC, j < 8);
  }

  // epilogue: D row = lo*4 + reg (cout), col = l15 (ow)
  const int oh = oh0 + wn;
  if (oh < NOH) {
    #pragma unroll
    for (int mi = 0; mi < 8; ++mi) {
      int co0 = cbase + mi * 16 + lo * 4;
      const f32x4 bv = *(const f32x4*)(bias + co0);
      #pragma unroll
      for (int ni = 0; ni < 4; ++ni) {
        int ow = ni * 16 + l15;
        if (ow < NOW) {
          size_t o0 = (((size_t)b * NCO + co0) * NOH + oh) * NOW + ow;
          const size_t cs = (size_t)NOH * NOW;
          out[o0]          = acc[mi][ni][0] + bv[0];
          out[o0 + cs]     = acc[mi][ni][1] + bv[1];
          out[o0 + 2 * cs] = acc[mi][ni][2] + bv[2];
          out[o0 + 3 * cs] = acc[mi][ni][3] + bv[3];
        }
      }
    }
  }
}

// Safety-net: correct fp32 direct conv (used only if ws_size too small)
__global__ __launch_bounds__(256) void conv_naive_kernel(
    const float* __restrict__ x, const float* __restrict__ w,
    const float* __restrict__ bias, float* __restrict__ out) {
  long t = (long)blockIdx.x * 256 + threadIdx.x;
  const long total = (long)NB * NCO * NOH * NOW;
  if (t >= total) return;
  int ow = (int)(t % NOW);
  int oh = (int)((t / NOW) % NOH);
  int co = (int)((t / ((long)NOW * NOH)) % NCO);
  int b  = (int)(t / ((long)NOW * NOH * NCO));
  float acc = bias[co];
  for (int ci = 0; ci < NCI; ++ci) {
    const float* xp = x + (((size_t)b * NCI + ci) * NH + oh) * NW + ow;
    const float* wp = w + ((size_t)co * NCI + ci) * 9;
    #pragma unroll
    for (int kh = 0; kh < 3; ++kh)
      #pragma unroll
      for (int kw = 0; kw < 3; ++kw)
        acc += xp[kh * NW + kw] * wp[kh * 3 + kw];
  }
  out[t] = acc;
}

extern "C" void kernel_launch(void* const* d_in, const int* in_sizes, int n_in,
                              void* d_out, int out_size, void* d_ws, size_t ws_size,
                              hipStream_t stream) {
  const float* x    = (const float*)d_in[0];
  const float* w    = (const float*)d_in[1];
  const float* bias = (const float*)d_in[2];
  float* out        = (float*)d_out;

  const size_t WT_BYTES = (size_t)9 * NCO * NCI * 2;             // 589824
  const size_t XT_BYTES = (size_t)NB * NH * NW * NCI * 2;        // 33554432

  if (ws_size >= WT_BYTES + XT_BYTES) {
    unsigned short* wt = (unsigned short*)d_ws;
    unsigned short* xt = (unsigned short*)((char*)d_ws + WT_BYTES);
    cvt_w_kernel<<<(9 * NCO * 16) / 256, 256, 0, stream>>>(w, wt);
    cvt_x_kernel<<<NB * NH, 256, 0, stream>>>(x, xt);
    conv_mfma_kernel<<<2 * 16 * NB, 256, 0, stream>>>(xt, wt, bias, out);
  } else {
    const long total = (long)NB * NCO * NOH * NOW;
    conv_naive_kernel<<<(int)((total + 255) / 256), 256, 0, stream>>>(x, w, bias, out);
  }
}

// Round 14
// 88.830 us; speedup vs baseline: 1.1374x; 1.0704x over previous
//
#include <hip/hip_runtime.h>

#define NB   32
#define NCI  128
#define NH   64
#define NW   64
#define NCO  256
#define NOH  62
#define NOW  62

typedef __attribute__((ext_vector_type(8))) short bf16x8;           // 8 bf16 (4 VGPRs)
typedef __attribute__((ext_vector_type(8))) unsigned short u16x8;
typedef __attribute__((ext_vector_type(4))) float f32x4;

typedef __attribute__((address_space(1))) const unsigned int glb_u32_t;
typedef __attribute__((address_space(3))) unsigned int lds_u32_t;

// fp32 -> bf16 bits, round-to-nearest-even (finite inputs)
__device__ __forceinline__ unsigned short f2bf(float f) {
  unsigned int u = __float_as_uint(f);
  u = u + 0x7FFFu + ((u >> 16) & 1u);
  return (unsigned short)(u >> 16);
}

__device__ __forceinline__ void gload_lds16(const unsigned short* g, unsigned short* l) {
  __builtin_amdgcn_global_load_lds((glb_u32_t*)g, (lds_u32_t*)l, 16, 0, 0);
}

// W[co][ci][kh][kw] fp32 -> wt[k][co][ci] bf16, coalesced 16B stores
__global__ __launch_bounds__(256) void cvt_w_kernel(const float* __restrict__ wsrc,
                                                    unsigned short* __restrict__ wt) {
  int t = blockIdx.x * 256 + threadIdx.x;            // 0 .. 9*256*16-1
  int oc = t & 15, co = (t >> 4) & 255, k = t >> 12;
  const float* src = wsrc + ((size_t)co * NCI + oc * 8) * 9 + k;
  u16x8 v;
  #pragma unroll
  for (int j = 0; j < 8; ++j) v[j] = f2bf(src[j * 9]);
  *(u16x8*)(wt + ((size_t)k * NCO + co) * NCI + oc * 8) = v;
}

// Implicit direct conv, bf16 MFMA 16x16x32 — half-tap pipeline (R13) with the
// x fp32->bf16 TRANSPOSE FUSED into conv staging (cvt_x kernel eliminated;
// it was a ~16 us BW-floor pre-pass). Per chunk, each thread loads 48
// coalesced fp32 dwords (w = lane), converts with the same f2bf rounding,
// and stores 6 swizzled ds_write_b128 -- one 8-elem unit per tap over
// t9 in {2..7} (8 VGPR live per tap). bf frags are single-buffered (read at
// tap end, after bfC's last use) to free the 16 VGPR the old bfD needed:
// unified budget is exactly 256/wave (128 acc AGPR + 128 VGPR) at 2 w/SIMD.
// Block: 256 thr (4 waves wn 0..3), tile 128 cout x 4 oh x 64 ow;
// wave tile 128co x 64pix (8m x 4n). 36 taps t = c*9 + t9. LDS 80 KB:
//   xs: 2 x [6r][64w][4oct][8] (24 KB, parity c&1)  bytes [0, 49152)
//   ws: 4 x [128co][4oct][8]   (8 KB, slot t&3)     bytes [49152, 81920)
// ws staging depth 3 (gload_lds, stage t+3 at tap t top); x unit loads issued
// BEFORE stage_w so the tap-end vmcnt(2) retires [ws(t+2) + x8] while keeping
// ws(t+3) in flight. lgkmcnt(0) before the barrier on staging taps makes the
// ds_write cross-wave visible; first reader is >=1 barrier + 1 full tap later.
// xs WAR: chunk c+1 parity = chunk c-1 parity, last read at end of tap 9c-1;
// first write at end of tap 9c+2 (3 barriers later). RAW: last write at end
// of tap 9c+7; first read at end of tap 9c+8 (1 barrier + full tap later).
// Octet swizzle on both sides (linear-dest rule only constrains gload_lds;
// ds_write is free scatter); write pattern is bank-even (8 dwords/bank).
// xs w-overreads (w up to 65) stay in-allocation, feed masked ow>=62 only.
__global__ __launch_bounds__(256, 2) void conv_mfma_kernel(
    const float* __restrict__ x, const unsigned short* __restrict__ wt,
    const float* __restrict__ bias, float* __restrict__ out) {
  __shared__ unsigned short smem[40960];   // 81920 B

  const int tid  = threadIdx.x;
  const int lane = tid & 63;
  const int wid  = tid >> 6;    // 0..3
  const int wn   = wid;         // output row within quad (0..3)
  const int l15  = lane & 15;
  const int lo   = lane >> 4;   // k-octet group

  // XCD-bijective swizzle: grid 1024 = 8 * 128 exactly.
  const int bid0  = blockIdx.x;
  const int bid   = (bid0 & 7) * 128 + (bid0 >> 3);
  const int coutg = bid & 1;               // ((b*16 + ohg)*2 + coutg)
  const int ohg   = (bid >> 1) & 15;
  const int b     = bid >> 5;
  const int cbase = coutg * 128;
  const int oh0   = ohg * 4;               // 0..60 (ohg 15: rows 62,63 masked)

  f32x4 acc[8][4];
  #pragma unroll
  for (int mi = 0; mi < 8; ++mi)
    #pragma unroll
    for (int ni = 0; ni < 4; ++ni)
      acc[mi][ni] = (f32x4){0.f, 0.f, 0.f, 0.f};

  // per-lane LDS read base (bytes); mi/ni terms are static offsets
  const char* sm = (const char*)smem;
  const int af_lane = l15 * 64 + ((lo ^ ((l15 >> 1) & 3)) << 4);

  // x fp32 base for this batch image
  const float* xb = x + ((size_t)b * NCI) * (NH * NW);

  const unsigned short* wsrc2[2];
  #pragma unroll
  for (int i = 0; i < 2; ++i) {
    int e = (wid * 2 + i) * 64 + lane;     // 0..511
    int o = e & 3, co = e >> 2;            // co 0..127
    wsrc2[i] = wt + (size_t)(cbase + co) * NCI + ((o ^ ((co >> 1) & 3)) * 8);
  }

  // stage ws for global tap t into slot t&3: 2 gload/thread
  auto stage_w = [&](int t) {
    unsigned short* dst = smem + 24576 + (t & 3) * 4096;
    const size_t so = (size_t)(t % 9) * NCO * NCI + (t / 9) * 32;
    #pragma unroll
    for (int i = 0; i < 2; ++i)
      gload_lds16(wsrc2[i] + so, dst + ((wid * 2 + i) * 64 + lane) * 8);
  };

  // fused x staging: unit uu of chunk c1 = (row r, ci-octet oct, w = lane)
  auto xload8 = [&](int c1, int uu, float (&xf)[8]) {
    const int g = uu * 4 + wid;            // 0..23
    const int r = g % 6, oct = g / 6;
    int row = oh0 + r; if (row > 63) row = 63;       // clamp (masked outputs)
    const float* src = xb + (size_t)(c1 * 32 + oct * 8) * (NH * NW)
                     + row * NW + lane;
    #pragma unroll
    for (int j = 0; j < 8; ++j) xf[j] = src[(size_t)j * (NH * NW)];
  };
  auto xwrite8 = [&](int c1, int uu, float (&xf)[8]) {
    const int g = uu * 4 + wid;
    const int r = g % 6, oct = g / 6;
    u16x8 v;
    #pragma unroll
    for (int j = 0; j < 8; ++j) v[j] = f2bf(xf[j]);
    *(u16x8*)(smem + (c1 & 1) * 12288 +
              ((r * 64 + lane) * 4 + (oct ^ ((lane >> 1) & 3))) * 8) = v;
  };

  bf16x8 afX[4], afY[4], bfC[4];

  // prologue: chunk 0 (fused), ws slots 0,1,2; drain; initial frag fill
  {
    float xa[8], xbv[8], xc[8], xd[8], xe[8], xg[8];
    xload8(0, 0, xa); xload8(0, 1, xbv); xload8(0, 2, xc);
    xload8(0, 3, xd); xload8(0, 4, xe);  xload8(0, 5, xg);
    stage_w(0); stage_w(1); stage_w(2);
    asm volatile("s_waitcnt vmcnt(6)" ::: "memory");   // x48 retired
    xwrite8(0, 0, xa); xwrite8(0, 1, xbv); xwrite8(0, 2, xc);
    xwrite8(0, 3, xd); xwrite8(0, 4, xe);  xwrite8(0, 5, xg);
    asm volatile("s_waitcnt vmcnt(0) lgkmcnt(0)" ::: "memory");
    __builtin_amdgcn_s_barrier();
    __builtin_amdgcn_sched_barrier(0);
    const char* wsp0 = sm + 49152;
    #pragma unroll
    for (int i = 0; i < 4; ++i)
      afX[i] = *(const bf16x8*)(wsp0 + i * 1024 + af_lane);
    const char* xsp0 = sm + wn * 4096;     // t=0: c=0, kh=0, kw=0
    #pragma unroll
    for (int i = 0; i < 4; ++i)
      bfC[i] = *(const bf16x8*)(xsp0 + i * 1024 + af_lane);
  }

  for (int t = 0; t < 36; ++t) {
    const int t9 = t % 9, c = t / 9;
    const bool xst = (t9 >= 2 && t9 <= 7) && (c < 3);
    const bool pf  = (t < 35);
    float xf[8];

    // ---- tap top: x unit loads (oldest), then ws stage (stays in flight)
    if (xst) xload8(c + 1, t9 - 2, xf);
    __builtin_amdgcn_sched_barrier(0);
    if (t + 3 < 36) stage_w(t + 3);
    __builtin_amdgcn_sched_barrier(0);

    const char* wsp  = sm + 49152 + (t & 3) * 8192;        // this tap's ws
    const char* wspn = sm + 49152 + ((t + 1) & 3) * 8192;  // next tap's ws

    // ---- half 0: acc[0..3] += afX x bfC  ||  afY <- af[4:7](t)
    asm volatile("s_waitcnt lgkmcnt(0)" ::: "memory");
    __builtin_amdgcn_sched_barrier(0);
    __builtin_amdgcn_s_setprio(1);
    #pragma unroll
    for (int ni = 0; ni < 4; ++ni)
      acc[0][ni] = __builtin_amdgcn_mfma_f32_16x16x32_bf16(afX[0], bfC[ni], acc[0][ni], 0, 0, 0);
    afY[0] = *(const bf16x8*)(wsp + 4 * 1024 + af_lane);
    afY[1] = *(const bf16x8*)(wsp + 5 * 1024 + af_lane);
    #pragma unroll
    for (int ni = 0; ni < 4; ++ni)
      acc[1][ni] = __builtin_amdgcn_mfma_f32_16x16x32_bf16(afX[1], bfC[ni], acc[1][ni], 0, 0, 0);
    afY[2] = *(const bf16x8*)(wsp + 6 * 1024 + af_lane);
    afY[3] = *(const bf16x8*)(wsp + 7 * 1024 + af_lane);
    #pragma unroll
    for (int ni = 0; ni < 4; ++ni)
      acc[2][ni] = __builtin_amdgcn_mfma_f32_16x16x32_bf16(afX[2], bfC[ni], acc[2][ni], 0, 0, 0);
    #pragma unroll
    for (int ni = 0; ni < 4; ++ni)
      acc[3][ni] = __builtin_amdgcn_mfma_f32_16x16x32_bf16(afX[3], bfC[ni], acc[3][ni], 0, 0, 0);
    __builtin_amdgcn_s_setprio(0);

    // ---- half 1: acc[4..7] += afY x bfC  ||  afX <- af[0:3](t+1)
    asm volatile("s_waitcnt lgkmcnt(0)" ::: "memory");
    __builtin_amdgcn_sched_barrier(0);
    __builtin_amdgcn_s_setprio(1);
    #pragma unroll
    for (int ni = 0; ni < 4; ++ni)
      acc[4][ni] = __builtin_amdgcn_mfma_f32_16x16x32_bf16(afY[0], bfC[ni], acc[4][ni], 0, 0, 0);
    if (pf) {
      afX[0] = *(const bf16x8*)(wspn + 0 * 1024 + af_lane);
      afX[1] = *(const bf16x8*)(wspn + 1 * 1024 + af_lane);
    }
    #pragma unroll
    for (int ni = 0; ni < 4; ++ni)
      acc[5][ni] = __builtin_amdgcn_mfma_f32_16x16x32_bf16(afY[1], bfC[ni], acc[5][ni], 0, 0, 0);
    if (pf) {
      afX[2] = *(const bf16x8*)(wspn + 2 * 1024 + af_lane);
      afX[3] = *(const bf16x8*)(wspn + 3 * 1024 + af_lane);
    }
    #pragma unroll
    for (int ni = 0; ni < 4; ++ni)
      acc[6][ni] = __builtin_amdgcn_mfma_f32_16x16x32_bf16(afY[2], bfC[ni], acc[6][ni], 0, 0, 0);
    #pragma unroll
    for (int ni = 0; ni < 4; ++ni)
      acc[7][ni] = __builtin_amdgcn_mfma_f32_16x16x32_bf16(afY[3], bfC[ni], acc[7][ni], 0, 0, 0);
    __builtin_amdgcn_s_setprio(0);

    // ---- tap end: counted vmcnt; fused x cvt+write; bf read for t+1; barrier
    if (t >= 33) {
      asm volatile("s_waitcnt vmcnt(0)" ::: "memory");
    } else {
      asm volatile("s_waitcnt vmcnt(2)" ::: "memory");   // retires ws(t+2)+x8
    }
    if (xst) xwrite8(c + 1, t9 - 2, xf);
    if (pf) {                                  // bfC <- bf(t+1), after last use
      const int tn = t + 1, tn9 = tn % 9, cn = tn / 9;
      const int khn = tn9 / 3, kwn = tn9 - khn * 3;
      const char* xspn = sm + (cn & 1) * 24576 + (wn + khn) * 4096;
      const int w9n = l15 + kwn;
      const int bfln = w9n * 64 + ((lo ^ ((w9n >> 1) & 3)) << 4);
      #pragma unroll
      for (int i = 0; i < 4; ++i)
        bfC[i] = *(const bf16x8*)(xspn + i * 1024 + bfln);
    }
    if (xst) asm volatile("s_waitcnt lgkmcnt(4)" ::: "memory");  // ds_writes landed (bf reads may fly)
    __builtin_amdgcn_s_barrier();
    __builtin_amdgcn_sched_barrier(0);
  }

  // epilogue: D row = lo*4 + reg (cout), col = l15 (ow)
  const int oh = oh0 + wn;
  if (oh < NOH) {
    #pragma unroll
    for (int mi = 0; mi < 8; ++mi) {
      int co0 = cbase + mi * 16 + lo * 4;
      const f32x4 bv = *(const f32x4*)(bias + co0);
      #pragma unroll
      for (int ni = 0; ni < 4; ++ni) {
        int ow = ni * 16 + l15;
        if (ow < NOW) {
          size_t o0 = (((size_t)b * NCO + co0) * NOH + oh) * NOW + ow;
          const size_t cs = (size_t)NOH * NOW;
          out[o0]          = acc[mi][ni][0] + bv[0];
          out[o0 + cs]     = acc[mi][ni][1] + bv[1];
          out[o0 + 2 * cs] = acc[mi][ni][2] + bv[2];
          out[o0 + 3 * cs] = acc[mi][ni][3] + bv[3];
        }
      }
    }
  }
}

// Safety-net: correct fp32 direct conv (used only if ws_size too small)
__global__ __launch_bounds__(256) void conv_naive_kernel(
    const float* __restrict__ x, const float* __restrict__ w,
    const float* __restrict__ bias, float* __restrict__ out) {
  long t = (long)blockIdx.x * 256 + threadIdx.x;
  const long total = (long)NB * NCO * NOH * NOW;
  if (t >= total) return;
  int ow = (int)(t % NOW);
  int oh = (int)((t / NOW) % NOH);
  int co = (int)((t / ((long)NOW * NOH)) % NCO);
  int b  = (int)(t / ((long)NOW * NOH * NCO));
  float acc = bias[co];
  for (int ci = 0; ci < NCI; ++ci) {
    const float* xp = x + (((size_t)b * NCI + ci) * NH + oh) * NW + ow;
    const float* wp = w + ((size_t)co * NCI + ci) * 9;
    #pragma unroll
    for (int kh = 0; kh < 3; ++kh)
      #pragma unroll
      for (int kw = 0; kw < 3; ++kw)
        acc += xp[kh * NW + kw] * wp[kh * 3 + kw];
  }
  out[t] = acc;
}

extern "C" void kernel_launch(void* const* d_in, const int* in_sizes, int n_in,
                              void* d_out, int out_size, void* d_ws, size_t ws_size,
                              hipStream_t stream) {
  const float* x    = (const float*)d_in[0];
  const float* w    = (const float*)d_in[1];
  const float* bias = (const float*)d_in[2];
  float* out        = (float*)d_out;

  const size_t WT_BYTES = (size_t)9 * NCO * NCI * 2;             // 589824

  if (ws_size >= WT_BYTES) {
    unsigned short* wt = (unsigned short*)d_ws;
    cvt_w_kernel<<<(9 * NCO * 16) / 256, 256, 0, stream>>>(w, wt);
    conv_mfma_kernel<<<2 * 16 * NB, 256, 0, stream>>>(x, wt, bias, out);
  } else {
    const long total = (long)NB * NCO * NOH * NOW;
    conv_naive_kernel<<<(int)((total + 255) / 256), 256, 0, stream>>>(x, w, bias, out);
  }
}